// Round 7
// baseline (342.495 us; speedup 1.0000x reference)
//
#include <hip/hip_runtime.h>
#include <hip/hip_cooperative_groups.h>
#include <math.h>

#define CC 512
#define CB 128
#define BB 32
#define HW 4096
#define NROW (BB * CC)            // 16384 rows
#define ROWS_PB 32                // rows per block
#define NBLK (NROW / ROWS_PB)     // 512 blocks = 2 per CU
#define NTHR 256
#define LDSROWS 7                 // rows kept in LDS   (7*4096*2B = 57344 B)
#define REGROWS (ROWS_PB - LDSROWS)  // 25 rows in registers
#define CHUNKS 4                  // 4-elem chunks per row per thread (4096/4/256)

typedef float f32x4 __attribute__((ext_vector_type(4)));
typedef unsigned short u16x4 __attribute__((ext_vector_type(4)));

static __device__ __forceinline__ unsigned short f2bf(float x) {
    unsigned u = __float_as_uint(x);
    unsigned r = (u + 0x7fffu + ((u >> 16) & 1u)) >> 16;   // RNE
    return (unsigned short)r;
}
static __device__ __forceinline__ float bf2f(unsigned short b) {
    return __uint_as_float(((unsigned)b) << 16);
}

// ============ single-pass fused SE kernel (cooperative) ============
__global__ __launch_bounds__(NTHR, 2) void se_fused(
    const float* __restrict__ in, const float* __restrict__ w1,
    const float* __restrict__ b1, const float* __restrict__ gamma,
    const float* __restrict__ beta, const float* __restrict__ w2,
    const float* __restrict__ b2, float* __restrict__ out,
    float* __restrict__ s, float* __restrict__ hn)
{
    __shared__ unsigned short ldat[LDSROWS * HW];   // 57344 B bf16 data
    __shared__ float redbuf[ROWS_PB][4];            // row-sum partials / BN scratch
    __shared__ float hrow[BB];                      // middle-h scratch
    __shared__ float grow[ROWS_PB];                 // per-row gate

    const int t   = threadIdx.x;
    const int blk = blockIdx.x;
    const int R0  = blk * ROWS_PB;
    const int wv  = t >> 6, ln = t & 63;

    u16x4 dreg[REGROWS * CHUNKS];   // 100 x 2 VGPR = 200 VGPRs of retained data

    // ---------------- phase 1: pure read stream; pool + retain bf16 ----------------
#pragma unroll
    for (int lr = 0; lr < ROWS_PB; ++lr) {
        const f32x4* rp = (const f32x4*)(in + (size_t)(R0 + lr) * HW);
        float part = 0.f;
#pragma unroll
        for (int j = 0; j < CHUNKS; ++j) {
            f32x4 v = rp[t + j * NTHR];
            part += v.x + v.y + v.z + v.w;
            u16x4 cv;
            cv.x = f2bf(v.x); cv.y = f2bf(v.y); cv.z = f2bf(v.z); cv.w = f2bf(v.w);
            if (lr < LDSROWS) {
                *(u16x4*)&ldat[lr * HW + (t + j * NTHR) * 4] = cv;  // 8B/lane, 2-way bank (free)
            } else {
                dreg[(lr - LDSROWS) * CHUNKS + j] = cv;             // static index
            }
        }
#pragma unroll
        for (int off = 32; off >= 1; off >>= 1)
            part += __shfl_xor(part, off, 64);
        if (ln == 0) redbuf[lr][wv] = part;
    }
    __syncthreads();
    if (t < ROWS_PB) {
        float sum = redbuf[t][0] + redbuf[t][1] + redbuf[t][2] + redbuf[t][3];
        s[R0 + t] = sum * (1.0f / HW);
    }
    __threadfence();
    cooperative_groups::this_grid().sync();

    // ---------------- middle A: blocks 0..127 compute h[:,k] + BN -> hn ----------------
    if (blk < CB) {
        const int k = blk;
        const int b = t >> 3, p = t & 7;            // 32 b's x 8-way split of 512-dot
        const f32x4* sr = (const f32x4*)(s  + b * CC + p * 64);
        const f32x4* wr = (const f32x4*)(w1 + k * CC + p * 64);
        float acc = 0.f;
#pragma unroll
        for (int j = 0; j < 16; ++j) {
            f32x4 a = sr[j], w = wr[j];
            acc += a.x * w.x + a.y * w.y + a.z * w.z + a.w * w.w;
        }
        acc += __shfl_xor(acc, 1, 64);
        acc += __shfl_xor(acc, 2, 64);
        acc += __shfl_xor(acc, 4, 64);
        if (p == 0) {
            float v = acc + b1[k];
            hrow[b] = v > 0.f ? v : 0.f;
        }
        __syncthreads();
        if (t == 0) {
            float su = 0.f, sq = 0.f;
            for (int bb = 0; bb < BB; ++bb) { float v = hrow[bb]; su += v; sq += v * v; }
            float mu  = su * (1.0f / BB);
            float var = sq * (1.0f / BB) - mu * mu;
            redbuf[0][0] = mu;
            redbuf[0][1] = gamma[k] * rsqrtf(var + 1e-5f);
        }
        __syncthreads();
        if (t < BB) {
            float mu = redbuf[0][0], sc = redbuf[0][1];
            hn[t * CB + k] = (hrow[t] - mu) * sc + beta[k];
        }
    }
    __threadfence();
    cooperative_groups::this_grid().sync();

    // ---------------- middle B: every block computes g for its own 32 rows ----------------
    {
        const int r = t >> 3, p = t & 7;            // 32 rows x 8-way split of 128-dot
        const int R = R0 + r;
        const int bb = R >> 9, cc = R & 511;
        const f32x4* hr = (const f32x4*)(hn + bb * CB + p * 16);
        const f32x4* wr = (const f32x4*)(w2 + cc * CB + p * 16);
        float acc = 0.f;
#pragma unroll
        for (int j = 0; j < 4; ++j) {
            f32x4 a = hr[j], w = wr[j];
            acc += a.x * w.x + a.y * w.y + a.z * w.z + a.w * w.w;
        }
        acc += __shfl_xor(acc, 1, 64);
        acc += __shfl_xor(acc, 2, 64);
        acc += __shfl_xor(acc, 4, 64);
        if (p == 0) grow[r] = 1.0f / (1.0f + expf(-(acc + b2[cc])));
    }
    __syncthreads();

    // ---------------- phase 2: pure NT write stream from retained bf16 ----------------
#pragma unroll
    for (int lr = 0; lr < ROWS_PB; ++lr) {
        float g = grow[lr];
        f32x4* op = (f32x4*)(out + (size_t)(R0 + lr) * HW);
#pragma unroll
        for (int j = 0; j < CHUNKS; ++j) {
            u16x4 cv;
            if (lr < LDSROWS) {
                cv = *(const u16x4*)&ldat[lr * HW + (t + j * NTHR) * 4];
            } else {
                cv = dreg[(lr - LDSROWS) * CHUNKS + j];
            }
            f32x4 v;
            v.x = bf2f(cv.x) * g;
            v.y = bf2f(cv.y) * g;
            v.z = bf2f(cv.z) * g;
            v.w = bf2f(cv.w) * g;
            __builtin_nontemporal_store(v, &op[t + j * NTHR]);
        }
    }
}

// ============ fallback path (R3 structure) ============
__global__ __launch_bounds__(256) void se_pool(const float* __restrict__ in,
                                               float* __restrict__ s) {
    int bc = blockIdx.x;
    const f32x4* row = (const f32x4*)(in + (size_t)bc * HW);
    int t = threadIdx.x;
    float acc = 0.f;
#pragma unroll
    for (int i = 0; i < 4; ++i) {
        f32x4 v = row[t + i * 256];
        acc += v.x + v.y + v.z + v.w;
    }
#pragma unroll
    for (int off = 32; off >= 1; off >>= 1)
        acc += __shfl_xor(acc, off, 64);
    __shared__ float red[4];
    if ((t & 63) == 0) red[t >> 6] = acc;
    __syncthreads();
    if (t == 0) s[bc] = (red[0] + red[1] + red[2] + red[3]) * (1.0f / HW);
}

__global__ __launch_bounds__(256) void se_h(const float* __restrict__ s,
                                            const float* __restrict__ w1,
                                            const float* __restrict__ b1,
                                            float* __restrict__ h) {
    int k = blockIdx.x;
    __shared__ float wrow[CC];
    int t = threadIdx.x;
    wrow[t]       = w1[k * CC + t];
    wrow[t + 256] = w1[k * CC + t + 256];
    __syncthreads();
    int b = t >> 3, p = t & 7;
    const float* srow = s + b * CC + p * 64;
    const float* wp   = wrow + p * 64;
    float acc = 0.f;
#pragma unroll
    for (int j = 0; j < 64; ++j) acc += srow[j] * wp[j];
    acc += __shfl_xor(acc, 1, 64);
    acc += __shfl_xor(acc, 2, 64);
    acc += __shfl_xor(acc, 4, 64);
    if (p == 0) {
        float v = acc + b1[k];
        h[b * CB + k] = v > 0.f ? v : 0.f;
    }
}

__global__ __launch_bounds__(128) void se_bn(float* __restrict__ h,
                                             const float* __restrict__ gamma,
                                             const float* __restrict__ beta) {
    int k = threadIdx.x;
    float sum = 0.f, sumsq = 0.f;
#pragma unroll
    for (int b = 0; b < BB; ++b) {
        float v = h[b * CB + k];
        sum += v; sumsq += v * v;
    }
    float mu  = sum * (1.0f / BB);
    float var = sumsq * (1.0f / BB) - mu * mu;
    float sc  = gamma[k] * rsqrtf(var + 1e-5f);
    float sh  = beta[k] - mu * sc;
#pragma unroll
    for (int b = 0; b < BB; ++b)
        h[b * CB + k] = h[b * CB + k] * sc + sh;
}

__global__ __launch_bounds__(256) void se_mul(const float* __restrict__ in,
                                              const float* __restrict__ hn,
                                              const float* __restrict__ w2,
                                              const float* __restrict__ b2,
                                              float* __restrict__ out) {
    int bc = (NROW - 1) - blockIdx.x;
    int b = bc >> 9, c = bc & 511;
    const f32x4* hv = (const f32x4*)(hn + b * CB);
    const f32x4* wv = (const f32x4*)(w2 + c * CB);
    float acc = 0.f;
#pragma unroll
    for (int i = 0; i < 32; ++i) {
        f32x4 a = hv[i], w = wv[i];
        acc += a.x * w.x + a.y * w.y + a.z * w.z + a.w * w.w;
    }
    float g = 1.0f / (1.0f + expf(-(acc + b2[c])));
    const f32x4* iv = (const f32x4*)(in + (size_t)bc * HW);
    f32x4* ov       = (f32x4*)(out + (size_t)bc * HW);
    int t = threadIdx.x;
#pragma unroll
    for (int i = 0; i < 4; ++i) {
        f32x4 v = iv[t + i * 256];
        v.x *= g; v.y *= g; v.z *= g; v.w *= g;
        __builtin_nontemporal_store(v, &ov[t + i * 256]);
    }
}

extern "C" void kernel_launch(void* const* d_in, const int* in_sizes, int n_in,
                              void* d_out, int out_size, void* d_ws, size_t ws_size,
                              hipStream_t stream) {
    const float* in    = (const float*)d_in[0];
    const float* w1    = (const float*)d_in[1];
    const float* b1    = (const float*)d_in[2];
    const float* gamma = (const float*)d_in[3];
    const float* beta  = (const float*)d_in[4];
    const float* w2    = (const float*)d_in[5];
    const float* b2    = (const float*)d_in[6];
    float* out = (float*)d_out;

    float* s  = (float*)d_ws;      // 16384 floats (row means)
    float* hn = s + NROW;          // 32*128 floats (normalized h)

    void* args[] = { (void*)&in, (void*)&w1, (void*)&b1, (void*)&gamma,
                     (void*)&beta, (void*)&w2, (void*)&b2, (void*)&out,
                     (void*)&s, (void*)&hn };
    hipError_t e = hipLaunchCooperativeKernel((const void*)se_fused,
                                              dim3(NBLK), dim3(NTHR),
                                              args, 0, stream);
    if (e != hipSuccess) {
        // fallback: proven two-pass structure (~128 us)
        se_pool<<<NROW, 256, 0, stream>>>(in, s);
        se_h<<<CB, 256, 0, stream>>>(s, w1, b1, hn);
        se_bn<<<1, CB, 0, stream>>>(hn, gamma, beta);
        se_mul<<<NROW, 256, 0, stream>>>(in, hn, w2, b2, out);
    }
}

// Round 8
// 259.454 us; speedup vs baseline: 1.3201x; 1.3201x over previous
//
#include <hip/hip_runtime.h>
#include <math.h>

#define CC 512
#define CB 128
#define BB 32
#define HW 4096
#define NROW (BB * CC)            // 16384 rows
#define ROWS_PB 32                // rows per block
#define NBLK (NROW / ROWS_PB)     // 512 blocks = 2 per CU
#define NTHR 256
#define LDSROWS 7                 // rows kept in LDS (7*4096*2B = 57344 B)
#define REGROWS (ROWS_PB - LDSROWS)  // 25 rows in registers
#define CHUNKS 4                  // 4096 / 4 / 256

typedef float f32x4 __attribute__((ext_vector_type(4)));
typedef unsigned short u16x4 __attribute__((ext_vector_type(4)));

static __device__ __forceinline__ unsigned short f2bf(float x) {
    unsigned u = __float_as_uint(x);
    unsigned r = (u + 0x7fffu + ((u >> 16) & 1u)) >> 16;   // RNE
    return (unsigned short)r;
}
static __device__ __forceinline__ float bf2f(unsigned short b) {
    return __uint_as_float(((unsigned)b) << 16);
}

// Hand-inlined 2-level grid barrier: no function-call ABI -> no forced spills.
// bar layout: 8 leaf counters at 128B stride, root at bar[8*32].
// Counters are monotonic across generations; zeroed by hipMemsetAsync per launch.
static __device__ __forceinline__ void grid_barrier(unsigned* bar, unsigned gen) {
    __syncthreads();
    if (threadIdx.x == 0) {
        __threadfence();  // agent-scope release of this block's prior writes
        unsigned* leaf = bar + (blockIdx.x & 7) * 32;
        unsigned* root = bar + 8 * 32;
        unsigned prev = __hip_atomic_fetch_add(leaf, 1u, __ATOMIC_ACQ_REL,
                                               __HIP_MEMORY_SCOPE_AGENT);
        if (prev + 1 == gen * (NBLK / 8)) {
            __hip_atomic_fetch_add(root, 1u, __ATOMIC_ACQ_REL,
                                   __HIP_MEMORY_SCOPE_AGENT);
        }
        while (__hip_atomic_load(root, __ATOMIC_ACQUIRE,
                                 __HIP_MEMORY_SCOPE_AGENT) < gen * 8u) {
            __builtin_amdgcn_s_sleep(4);
        }
    }
    __syncthreads();
}

// ============ single-pass fused SE kernel (cooperative co-residency) ============
__global__ __launch_bounds__(NTHR, 2) __attribute__((amdgpu_waves_per_eu(2, 2)))
void se_fused(
    const float* __restrict__ in, const float* __restrict__ w1,
    const float* __restrict__ b1, const float* __restrict__ gamma,
    const float* __restrict__ beta, const float* __restrict__ w2,
    const float* __restrict__ b2, float* __restrict__ out,
    float* __restrict__ s, float* __restrict__ hn, unsigned* __restrict__ bar)
{
    __shared__ unsigned short ldat[LDSROWS * HW];   // 57344 B retained bf16
    __shared__ float redbuf[ROWS_PB][4];
    __shared__ float hrow[BB];
    __shared__ float grow[ROWS_PB];

    const int t   = threadIdx.x;
    const int blk = blockIdx.x;
    const int R0  = blk * ROWS_PB;
    const int wv  = t >> 6, ln = t & 63;

    u16x4 dreg[REGROWS * CHUNKS];   // 100 x 8B = 200 VGPRs retained data

    // ---------------- phase 1: pure read stream; pool + retain bf16 ----------------
#pragma unroll
    for (int lr = 0; lr < ROWS_PB; ++lr) {
        const f32x4* rp = (const f32x4*)(in + (size_t)(R0 + lr) * HW);
        float part = 0.f;
#pragma unroll
        for (int j = 0; j < CHUNKS; ++j) {
            f32x4 v = rp[t + j * NTHR];
            part += v.x + v.y + v.z + v.w;
            u16x4 cv;
            cv.x = f2bf(v.x); cv.y = f2bf(v.y); cv.z = f2bf(v.z); cv.w = f2bf(v.w);
            if (lr < LDSROWS) {
                *(u16x4*)&ldat[lr * HW + (t + j * NTHR) * 4] = cv;
            } else {
                dreg[(lr - LDSROWS) * CHUNKS + j] = cv;   // static index
            }
        }
#pragma unroll
        for (int off = 32; off >= 1; off >>= 1)
            part += __shfl_xor(part, off, 64);
        if (ln == 0) redbuf[lr][wv] = part;
    }
    __syncthreads();
    if (t < ROWS_PB) {
        float sum = redbuf[t][0] + redbuf[t][1] + redbuf[t][2] + redbuf[t][3];
        s[R0 + t] = sum * (1.0f / HW);
    }
    grid_barrier(bar, 1);

    // ---------------- middle A: blocks 0..127 compute h[:,k] + BN -> hn ----------------
    if (blk < CB) {
        const int k = blk;
        const int b = t >> 3, p = t & 7;
        const f32x4* sr = (const f32x4*)(s  + b * CC + p * 64);
        const f32x4* wr = (const f32x4*)(w1 + k * CC + p * 64);
        float acc = 0.f;
#pragma unroll
        for (int j = 0; j < 16; ++j) {
            f32x4 a = sr[j], w = wr[j];
            acc += a.x * w.x + a.y * w.y + a.z * w.z + a.w * w.w;
        }
        acc += __shfl_xor(acc, 1, 64);
        acc += __shfl_xor(acc, 2, 64);
        acc += __shfl_xor(acc, 4, 64);
        if (p == 0) {
            float v = acc + b1[k];
            hrow[b] = v > 0.f ? v : 0.f;
        }
        __syncthreads();
        if (t == 0) {
            float su = 0.f, sq = 0.f;
            for (int bb = 0; bb < BB; ++bb) { float v = hrow[bb]; su += v; sq += v * v; }
            float mu  = su * (1.0f / BB);
            float var = sq * (1.0f / BB) - mu * mu;
            redbuf[0][0] = mu;
            redbuf[0][1] = gamma[k] * rsqrtf(var + 1e-5f);
        }
        __syncthreads();
        if (t < BB) {
            float mu = redbuf[0][0], sc = redbuf[0][1];
            hn[t * CB + k] = (hrow[t] - mu) * sc + beta[k];
        }
    }
    grid_barrier(bar, 2);

    // ---------------- middle B: per-block gates for its own 32 rows ----------------
    {
        const int r = t >> 3, p = t & 7;
        const int R = R0 + r;
        const int bb = R >> 9, cc = R & 511;
        const f32x4* hr = (const f32x4*)(hn + bb * CB + p * 16);
        const f32x4* wr = (const f32x4*)(w2 + cc * CB + p * 16);
        float acc = 0.f;
#pragma unroll
        for (int j = 0; j < 4; ++j) {
            f32x4 a = hr[j], w = wr[j];
            acc += a.x * w.x + a.y * w.y + a.z * w.z + a.w * w.w;
        }
        acc += __shfl_xor(acc, 1, 64);
        acc += __shfl_xor(acc, 2, 64);
        acc += __shfl_xor(acc, 4, 64);
        if (p == 0) grow[r] = 1.0f / (1.0f + expf(-(acc + b2[cc])));
    }
    __syncthreads();

    // ---------------- phase 2: pure NT write stream from retained bf16 ----------------
#pragma unroll
    for (int lr = 0; lr < ROWS_PB; ++lr) {
        float g = grow[lr];
        f32x4* op = (f32x4*)(out + (size_t)(R0 + lr) * HW);
#pragma unroll
        for (int j = 0; j < CHUNKS; ++j) {
            u16x4 cv;
            if (lr < LDSROWS) {
                cv = *(const u16x4*)&ldat[lr * HW + (t + j * NTHR) * 4];
            } else {
                cv = dreg[(lr - LDSROWS) * CHUNKS + j];
            }
            f32x4 v;
            v.x = bf2f(cv.x) * g;
            v.y = bf2f(cv.y) * g;
            v.z = bf2f(cv.z) * g;
            v.w = bf2f(cv.w) * g;
            __builtin_nontemporal_store(v, &op[t + j * NTHR]);
        }
    }
}

// ============ fallback path (R3 structure, ~128 us) ============
__global__ __launch_bounds__(256) void se_pool(const float* __restrict__ in,
                                               float* __restrict__ s) {
    int bc = blockIdx.x;
    const f32x4* row = (const f32x4*)(in + (size_t)bc * HW);
    int t = threadIdx.x;
    float acc = 0.f;
#pragma unroll
    for (int i = 0; i < 4; ++i) {
        f32x4 v = row[t + i * 256];
        acc += v.x + v.y + v.z + v.w;
    }
#pragma unroll
    for (int off = 32; off >= 1; off >>= 1)
        acc += __shfl_xor(acc, off, 64);
    __shared__ float red[4];
    if ((t & 63) == 0) red[t >> 6] = acc;
    __syncthreads();
    if (t == 0) s[bc] = (red[0] + red[1] + red[2] + red[3]) * (1.0f / HW);
}

__global__ __launch_bounds__(256) void se_h(const float* __restrict__ s,
                                            const float* __restrict__ w1,
                                            const float* __restrict__ b1,
                                            float* __restrict__ h) {
    int k = blockIdx.x;
    __shared__ float wrow[CC];
    int t = threadIdx.x;
    wrow[t]       = w1[k * CC + t];
    wrow[t + 256] = w1[k * CC + t + 256];
    __syncthreads();
    int b = t >> 3, p = t & 7;
    const float* srow = s + b * CC + p * 64;
    const float* wp   = wrow + p * 64;
    float acc = 0.f;
#pragma unroll
    for (int j = 0; j < 64; ++j) acc += srow[j] * wp[j];
    acc += __shfl_xor(acc, 1, 64);
    acc += __shfl_xor(acc, 2, 64);
    acc += __shfl_xor(acc, 4, 64);
    if (p == 0) {
        float v = acc + b1[k];
        h[b * CB + k] = v > 0.f ? v : 0.f;
    }
}

__global__ __launch_bounds__(128) void se_bn(float* __restrict__ h,
                                             const float* __restrict__ gamma,
                                             const float* __restrict__ beta) {
    int k = threadIdx.x;
    float sum = 0.f, sumsq = 0.f;
#pragma unroll
    for (int b = 0; b < BB; ++b) {
        float v = h[b * CB + k];
        sum += v; sumsq += v * v;
    }
    float mu  = sum * (1.0f / BB);
    float var = sumsq * (1.0f / BB) - mu * mu;
    float sc  = gamma[k] * rsqrtf(var + 1e-5f);
    float sh  = beta[k] - mu * sc;
#pragma unroll
    for (int b = 0; b < BB; ++b)
        h[b * CB + k] = h[b * CB + k] * sc + sh;
}

__global__ __launch_bounds__(256) void se_mul(const float* __restrict__ in,
                                              const float* __restrict__ hn,
                                              const float* __restrict__ w2,
                                              const float* __restrict__ b2,
                                              float* __restrict__ out) {
    int bc = (NROW - 1) - blockIdx.x;
    int b = bc >> 9, c = bc & 511;
    const f32x4* hv = (const f32x4*)(hn + b * CB);
    const f32x4* wv = (const f32x4*)(w2 + c * CB);
    float acc = 0.f;
#pragma unroll
    for (int i = 0; i < 32; ++i) {
        f32x4 a = hv[i], w = wv[i];
        acc += a.x * w.x + a.y * w.y + a.z * w.z + a.w * w.w;
    }
    float g = 1.0f / (1.0f + expf(-(acc + b2[c])));
    const f32x4* iv = (const f32x4*)(in + (size_t)bc * HW);
    f32x4* ov       = (f32x4*)(out + (size_t)bc * HW);
    int t = threadIdx.x;
#pragma unroll
    for (int i = 0; i < 4; ++i) {
        f32x4 v = iv[t + i * 256];
        v.x *= g; v.y *= g; v.z *= g; v.w *= g;
        __builtin_nontemporal_store(v, &ov[t + i * 256]);
    }
}

extern "C" void kernel_launch(void* const* d_in, const int* in_sizes, int n_in,
                              void* d_out, int out_size, void* d_ws, size_t ws_size,
                              hipStream_t stream) {
    const float* in    = (const float*)d_in[0];
    const float* w1    = (const float*)d_in[1];
    const float* b1    = (const float*)d_in[2];
    const float* gamma = (const float*)d_in[3];
    const float* beta  = (const float*)d_in[4];
    const float* w2    = (const float*)d_in[5];
    const float* b2    = (const float*)d_in[6];
    float* out = (float*)d_out;

    unsigned* bar = (unsigned*)d_ws;                       // 4 KB barrier counters
    float* s  = (float*)((char*)d_ws + 4096);              // 16384 floats
    float* hn = s + NROW;                                  // 4096 floats

    // zero barrier counters every call (graph-legal, deterministic)
    hipMemsetAsync(bar, 0, 4096, stream);

    void* args[] = { (void*)&in, (void*)&w1, (void*)&b1, (void*)&gamma,
                     (void*)&beta, (void*)&w2, (void*)&b2, (void*)&out,
                     (void*)&s, (void*)&hn, (void*)&bar };
    hipError_t e = hipLaunchCooperativeKernel((const void*)se_fused,
                                              dim3(NBLK), dim3(NTHR),
                                              args, 0, stream);
    if (e != hipSuccess) {
        // fallback: proven two-pass structure (~128 us)
        se_pool<<<NROW, 256, 0, stream>>>(in, s);
        se_h<<<CB, 256, 0, stream>>>(s, w1, b1, hn);
        se_bn<<<1, CB, 0, stream>>>(hn, gamma, beta);
        se_mul<<<NROW, 256, 0, stream>>>(in, hn, w2, b2, out);
    }
}

// Round 9
// 240.901 us; speedup vs baseline: 1.4217x; 1.0770x over previous
//
#include <hip/hip_runtime.h>
#include <math.h>

#define CC 512
#define CB 128
#define BB 32
#define HW 4096
#define NROW (BB * CC)            // 16384 rows
#define ROWS_PB 32                // rows per block
#define NBLK (NROW / ROWS_PB)     // 512 blocks = 2 per CU
#define NTHR 256
#define LDSROWS 7                 // rows retained in LDS (7*4096*2B = 57344 B)
#define NREGR 20                  // rows retained in named registers
#define NRELOAD 5                 // rows re-read from HBM (phase-1 tail = L3-hot)

typedef float f32x4 __attribute__((ext_vector_type(4)));
typedef unsigned short u16x4 __attribute__((ext_vector_type(4)));

static __device__ __forceinline__ unsigned short f2bf(float x) {
    unsigned u = __float_as_uint(x);
    unsigned r = (u + 0x7fffu + ((u >> 16) & 1u)) >> 16;   // RNE
    return (unsigned short)r;
}
static __device__ __forceinline__ float bf2f(unsigned short b) {
    return __uint_as_float(((unsigned)b) << 16);
}
static __device__ __forceinline__ u16x4 cvt4(f32x4 v) {
    u16x4 c; c.x = f2bf(v.x); c.y = f2bf(v.y); c.z = f2bf(v.z); c.w = f2bf(v.w);
    return c;
}
static __device__ __forceinline__ f32x4 scl4(u16x4 c, float g) {
    f32x4 v;
    v.x = bf2f(c.x) * g; v.y = bf2f(c.y) * g;
    v.z = bf2f(c.z) * g; v.w = bf2f(c.w) * g;
    return v;
}

// Hand-inlined 2-level grid barrier (no call ABI -> no forced spills).
static __device__ __forceinline__ void grid_barrier(unsigned* bar, unsigned gen) {
    __syncthreads();
    if (threadIdx.x == 0) {
        __threadfence();
        unsigned* leaf = bar + (blockIdx.x & 7) * 32;
        unsigned* root = bar + 8 * 32;
        unsigned prev = __hip_atomic_fetch_add(leaf, 1u, __ATOMIC_ACQ_REL,
                                               __HIP_MEMORY_SCOPE_AGENT);
        if (prev + 1 == gen * (NBLK / 8)) {
            __hip_atomic_fetch_add(root, 1u, __ATOMIC_ACQ_REL,
                                   __HIP_MEMORY_SCOPE_AGENT);
        }
        while (__hip_atomic_load(root, __ATOMIC_ACQUIRE,
                                 __HIP_MEMORY_SCOPE_AGENT) < gen * 8u) {
            __builtin_amdgcn_s_sleep(4);
        }
    }
    __syncthreads();
}

#define REPEAT20(M) M(0) M(1) M(2) M(3) M(4) M(5) M(6) M(7) M(8) M(9) \
                    M(10) M(11) M(12) M(13) M(14) M(15) M(16) M(17) M(18) M(19)

// ============ single-pass fused SE kernel (cooperative co-residency) ============
__global__ __launch_bounds__(NTHR, 2) __attribute__((amdgpu_waves_per_eu(2, 2)))
void se_fused(
    const float* __restrict__ in, const float* __restrict__ w1,
    const float* __restrict__ b1, const float* __restrict__ gamma,
    const float* __restrict__ beta, const float* __restrict__ w2,
    const float* __restrict__ b2, float* __restrict__ out,
    float* __restrict__ s, float* __restrict__ hn, unsigned* __restrict__ bar)
{
    __shared__ unsigned short ldat[LDSROWS * HW];   // 57344 B retained bf16
    __shared__ float redbuf[ROWS_PB][4];
    __shared__ float hrow[BB];
    __shared__ float grow[ROWS_PB];

    const int t   = threadIdx.x;
    const int blk = blockIdx.x;
    const int R0  = blk * ROWS_PB;
    const int wv  = t >> 6, ln = t & 63;

    // 80 named u16x4 = 160 VGPRs of retained data. No array -> nothing to
    // demote to scratch; every access is a compile-time-named SSA value.
#define DECLR(i) u16x4 r##i##_0, r##i##_1, r##i##_2, r##i##_3;
    REPEAT20(DECLR)
#undef DECLR

    // ---------------- phase 1: pure read stream; pool + retain ----------------
    // order: LDS rows (0-6), reg rows (7-26), reload rows (27-31) LAST so the
    // chip-wide tail of the read stream (the reload rows, ~40MB) is L3-hot
    // when phase 2 re-reads it first.
    for (int lr = 0; lr < LDSROWS; ++lr) {
        const f32x4* rp = (const f32x4*)(in + (size_t)(R0 + lr) * HW);
        float part = 0.f;
#pragma unroll
        for (int j = 0; j < 4; ++j) {
            f32x4 v = rp[t + j * NTHR];
            part += v.x + v.y + v.z + v.w;
            *(u16x4*)&ldat[lr * HW + (t + j * NTHR) * 4] = cvt4(v);
        }
#pragma unroll
        for (int off = 32; off >= 1; off >>= 1)
            part += __shfl_xor(part, off, 64);
        if (ln == 0) redbuf[lr][wv] = part;
    }

#define P1REG(i) { \
    const f32x4* rp = (const f32x4*)(in + (size_t)(R0 + LDSROWS + (i)) * HW); \
    f32x4 v0 = rp[t], v1 = rp[t + 256], v2 = rp[t + 512], v3 = rp[t + 768]; \
    float part = (v0.x + v0.y + v0.z + v0.w) + (v1.x + v1.y + v1.z + v1.w) \
               + (v2.x + v2.y + v2.z + v2.w) + (v3.x + v3.y + v3.z + v3.w); \
    r##i##_0 = cvt4(v0); r##i##_1 = cvt4(v1); \
    r##i##_2 = cvt4(v2); r##i##_3 = cvt4(v3); \
    _Pragma("unroll") \
    for (int off = 32; off >= 1; off >>= 1) part += __shfl_xor(part, off, 64); \
    if (ln == 0) redbuf[LDSROWS + (i)][wv] = part; \
}
    REPEAT20(P1REG)
#undef P1REG

    for (int lr = 0; lr < NRELOAD; ++lr) {       // tail rows: sum only
        const int row = LDSROWS + NREGR + lr;
        const f32x4* rp = (const f32x4*)(in + (size_t)(R0 + row) * HW);
        float part = 0.f;
#pragma unroll
        for (int j = 0; j < 4; ++j) {
            f32x4 v = rp[t + j * NTHR];
            part += v.x + v.y + v.z + v.w;
        }
#pragma unroll
        for (int off = 32; off >= 1; off >>= 1)
            part += __shfl_xor(part, off, 64);
        if (ln == 0) redbuf[row][wv] = part;
    }

    __syncthreads();
    if (t < ROWS_PB) {
        float sum = redbuf[t][0] + redbuf[t][1] + redbuf[t][2] + redbuf[t][3];
        s[R0 + t] = sum * (1.0f / HW);
    }
    grid_barrier(bar, 1);

    // ---------------- middle A: blocks 0..127 compute h[:,k] + BN -> hn ----------------
    if (blk < CB) {
        const int k = blk;
        const int b = t >> 3, p = t & 7;
        const f32x4* sr = (const f32x4*)(s  + b * CC + p * 64);
        const f32x4* wr = (const f32x4*)(w1 + k * CC + p * 64);
        float acc = 0.f;
#pragma unroll
        for (int j = 0; j < 16; ++j) {
            f32x4 a = sr[j], w = wr[j];
            acc += a.x * w.x + a.y * w.y + a.z * w.z + a.w * w.w;
        }
        acc += __shfl_xor(acc, 1, 64);
        acc += __shfl_xor(acc, 2, 64);
        acc += __shfl_xor(acc, 4, 64);
        if (p == 0) {
            float v = acc + b1[k];
            hrow[b] = v > 0.f ? v : 0.f;
        }
        __syncthreads();
        if (t == 0) {
            float su = 0.f, sq = 0.f;
            for (int bb = 0; bb < BB; ++bb) { float v = hrow[bb]; su += v; sq += v * v; }
            float mu  = su * (1.0f / BB);
            float var = sq * (1.0f / BB) - mu * mu;
            redbuf[0][0] = mu;
            redbuf[0][1] = gamma[k] * rsqrtf(var + 1e-5f);
        }
        __syncthreads();
        if (t < BB) {
            float mu = redbuf[0][0], sc = redbuf[0][1];
            hn[t * CB + k] = (hrow[t] - mu) * sc + beta[k];
        }
    }
    grid_barrier(bar, 2);

    // ---------------- middle B: per-block gates for its own 32 rows ----------------
    {
        const int r = t >> 3, p = t & 7;
        const int R = R0 + r;
        const int bb = R >> 9, cc = R & 511;
        const f32x4* hr = (const f32x4*)(hn + bb * CB + p * 16);
        const f32x4* wr = (const f32x4*)(w2 + cc * CB + p * 16);
        float acc = 0.f;
#pragma unroll
        for (int j = 0; j < 4; ++j) {
            f32x4 a = hr[j], w = wr[j];
            acc += a.x * w.x + a.y * w.y + a.z * w.z + a.w * w.w;
        }
        acc += __shfl_xor(acc, 1, 64);
        acc += __shfl_xor(acc, 2, 64);
        acc += __shfl_xor(acc, 4, 64);
        if (p == 0) grow[r] = 1.0f / (1.0f + expf(-(acc + b2[cc])));
    }
    __syncthreads();

    // ---------------- phase 2: reload rows first (L3-hot), then LDS, then regs ----------------
    for (int lr = 0; lr < NRELOAD; ++lr) {
        const int row = LDSROWS + NREGR + lr;
        float g = grow[row];
        const f32x4* rp = (const f32x4*)(in + (size_t)(R0 + row) * HW);
        f32x4* op = (f32x4*)(out + (size_t)(R0 + row) * HW);
#pragma unroll
        for (int j = 0; j < 4; ++j) {
            f32x4 v = rp[t + j * NTHR];
            v.x *= g; v.y *= g; v.z *= g; v.w *= g;
            __builtin_nontemporal_store(v, &op[t + j * NTHR]);
        }
    }

    for (int lr = 0; lr < LDSROWS; ++lr) {
        float g = grow[lr];
        f32x4* op = (f32x4*)(out + (size_t)(R0 + lr) * HW);
#pragma unroll
        for (int j = 0; j < 4; ++j) {
            u16x4 cv = *(const u16x4*)&ldat[lr * HW + (t + j * NTHR) * 4];
            __builtin_nontemporal_store(scl4(cv, g), &op[t + j * NTHR]);
        }
    }

#define P2REG(i) { \
    float g = grow[LDSROWS + (i)]; \
    f32x4* op = (f32x4*)(out + (size_t)(R0 + LDSROWS + (i)) * HW); \
    __builtin_nontemporal_store(scl4(r##i##_0, g), &op[t]); \
    __builtin_nontemporal_store(scl4(r##i##_1, g), &op[t + 256]); \
    __builtin_nontemporal_store(scl4(r##i##_2, g), &op[t + 512]); \
    __builtin_nontemporal_store(scl4(r##i##_3, g), &op[t + 768]); \
}
    REPEAT20(P2REG)
#undef P2REG
}

// ============ fallback path (R3 structure, ~128 us) ============
__global__ __launch_bounds__(256) void se_pool(const float* __restrict__ in,
                                               float* __restrict__ s) {
    int bc = blockIdx.x;
    const f32x4* row = (const f32x4*)(in + (size_t)bc * HW);
    int t = threadIdx.x;
    float acc = 0.f;
#pragma unroll
    for (int i = 0; i < 4; ++i) {
        f32x4 v = row[t + i * 256];
        acc += v.x + v.y + v.z + v.w;
    }
#pragma unroll
    for (int off = 32; off >= 1; off >>= 1)
        acc += __shfl_xor(acc, off, 64);
    __shared__ float red[4];
    if ((t & 63) == 0) red[t >> 6] = acc;
    __syncthreads();
    if (t == 0) s[bc] = (red[0] + red[1] + red[2] + red[3]) * (1.0f / HW);
}

__global__ __launch_bounds__(256) void se_h(const float* __restrict__ s,
                                            const float* __restrict__ w1,
                                            const float* __restrict__ b1,
                                            float* __restrict__ h) {
    int k = blockIdx.x;
    __shared__ float wrow[CC];
    int t = threadIdx.x;
    wrow[t]       = w1[k * CC + t];
    wrow[t + 256] = w1[k * CC + t + 256];
    __syncthreads();
    int b = t >> 3, p = t & 7;
    const float* srow = s + b * CC + p * 64;
    const float* wp   = wrow + p * 64;
    float acc = 0.f;
#pragma unroll
    for (int j = 0; j < 64; ++j) acc += srow[j] * wp[j];
    acc += __shfl_xor(acc, 1, 64);
    acc += __shfl_xor(acc, 2, 64);
    acc += __shfl_xor(acc, 4, 64);
    if (p == 0) {
        float v = acc + b1[k];
        h[b * CB + k] = v > 0.f ? v : 0.f;
    }
}

__global__ __launch_bounds__(128) void se_bn(float* __restrict__ h,
                                             const float* __restrict__ gamma,
                                             const float* __restrict__ beta) {
    int k = threadIdx.x;
    float sum = 0.f, sumsq = 0.f;
#pragma unroll
    for (int b = 0; b < BB; ++b) {
        float v = h[b * CB + k];
        sum += v; sumsq += v * v;
    }
    float mu  = sum * (1.0f / BB);
    float var = sumsq * (1.0f / BB) - mu * mu;
    float sc  = gamma[k] * rsqrtf(var + 1e-5f);
    float sh  = beta[k] - mu * sc;
#pragma unroll
    for (int b = 0; b < BB; ++b)
        h[b * CB + k] = h[b * CB + k] * sc + sh;
}

__global__ __launch_bounds__(256) void se_mul(const float* __restrict__ in,
                                              const float* __restrict__ hn,
                                              const float* __restrict__ w2,
                                              const float* __restrict__ b2,
                                              float* __restrict__ out) {
    int bc = (NROW - 1) - blockIdx.x;
    int b = bc >> 9, c = bc & 511;
    const f32x4* hv = (const f32x4*)(hn + b * CB);
    const f32x4* wv = (const f32x4*)(w2 + c * CB);
    float acc = 0.f;
#pragma unroll
    for (int i = 0; i < 32; ++i) {
        f32x4 a = hv[i], w = wv[i];
        acc += a.x * w.x + a.y * w.y + a.z * w.z + a.w * w.w;
    }
    float g = 1.0f / (1.0f + expf(-(acc + b2[c])));
    const f32x4* iv = (const f32x4*)(in + (size_t)bc * HW);
    f32x4* ov       = (f32x4*)(out + (size_t)bc * HW);
    int t = threadIdx.x;
#pragma unroll
    for (int i = 0; i < 4; ++i) {
        f32x4 v = iv[t + i * 256];
        v.x *= g; v.y *= g; v.z *= g; v.w *= g;
        __builtin_nontemporal_store(v, &ov[t + i * 256]);
    }
}

extern "C" void kernel_launch(void* const* d_in, const int* in_sizes, int n_in,
                              void* d_out, int out_size, void* d_ws, size_t ws_size,
                              hipStream_t stream) {
    const float* in    = (const float*)d_in[0];
    const float* w1    = (const float*)d_in[1];
    const float* b1    = (const float*)d_in[2];
    const float* gamma = (const float*)d_in[3];
    const float* beta  = (const float*)d_in[4];
    const float* w2    = (const float*)d_in[5];
    const float* b2    = (const float*)d_in[6];
    float* out = (float*)d_out;

    unsigned* bar = (unsigned*)d_ws;                       // 4 KB barrier counters
    float* s  = (float*)((char*)d_ws + 4096);              // 16384 floats
    float* hn = s + NROW;                                  // 4096 floats

    hipMemsetAsync(bar, 0, 4096, stream);                  // graph-legal, per-call

    void* args[] = { (void*)&in, (void*)&w1, (void*)&b1, (void*)&gamma,
                     (void*)&beta, (void*)&w2, (void*)&b2, (void*)&out,
                     (void*)&s, (void*)&hn, (void*)&bar };
    hipError_t e = hipLaunchCooperativeKernel((const void*)se_fused,
                                              dim3(NBLK), dim3(NTHR),
                                              args, 0, stream);
    if (e != hipSuccess) {
        se_pool<<<NROW, 256, 0, stream>>>(in, s);
        se_h<<<CB, 256, 0, stream>>>(s, w1, b1, hn);
        se_bn<<<1, CB, 0, stream>>>(hn, gamma, beta);
        se_mul<<<NROW, 256, 0, stream>>>(in, hn, w2, b2, out);
    }
}

// Round 10
// 211.003 us; speedup vs baseline: 1.6232x; 1.1417x over previous
//
#include <hip/hip_runtime.h>
#include <math.h>

#define CC 512
#define CB 128
#define BB 32
#define HW 4096
#define NROW (BB * CC)            // 16384 rows
#define ROWS_PB 32                // rows per block
#define NBLK (NROW / ROWS_PB)     // 512 blocks = 2 per CU
#define NTHR 256
#define NREGR 10                  // rows retained in named registers (80 VGPRs)
#define LDSROWS 7                 // rows retained in LDS (57344 B)
#define NRELOAD 15                // rows re-read (phase-1 tail -> L3-hot)
// local row map: [0,10)=reg, [10,17)=LDS, [17,32)=reload

typedef float f32x4 __attribute__((ext_vector_type(4)));
typedef unsigned short u16x4 __attribute__((ext_vector_type(4)));

static __device__ __forceinline__ unsigned short f2bf(float x) {
    unsigned u = __float_as_uint(x);
    unsigned r = (u + 0x7fffu + ((u >> 16) & 1u)) >> 16;   // RNE
    return (unsigned short)r;
}
static __device__ __forceinline__ float bf2f(unsigned short b) {
    return __uint_as_float(((unsigned)b) << 16);
}
static __device__ __forceinline__ u16x4 cvt4(f32x4 v) {
    u16x4 c; c.x = f2bf(v.x); c.y = f2bf(v.y); c.z = f2bf(v.z); c.w = f2bf(v.w);
    return c;
}
static __device__ __forceinline__ f32x4 scl4(u16x4 c, float g) {
    f32x4 v;
    v.x = bf2f(c.x) * g; v.y = bf2f(c.y) * g;
    v.z = bf2f(c.z) * g; v.w = bf2f(c.w) * g;
    return v;
}

// Hand-inlined 2-level grid barrier (no call ABI -> no forced spills).
static __device__ __forceinline__ void grid_barrier(unsigned* bar, unsigned gen) {
    __syncthreads();
    if (threadIdx.x == 0) {
        __threadfence();
        unsigned* leaf = bar + (blockIdx.x & 7) * 32;
        unsigned* root = bar + 8 * 32;
        unsigned prev = __hip_atomic_fetch_add(leaf, 1u, __ATOMIC_ACQ_REL,
                                               __HIP_MEMORY_SCOPE_AGENT);
        if (prev + 1 == gen * (NBLK / 8)) {
            __hip_atomic_fetch_add(root, 1u, __ATOMIC_ACQ_REL,
                                   __HIP_MEMORY_SCOPE_AGENT);
        }
        while (__hip_atomic_load(root, __ATOMIC_ACQUIRE,
                                 __HIP_MEMORY_SCOPE_AGENT) < gen * 8u) {
            __builtin_amdgcn_s_sleep(4);
        }
    }
    __syncthreads();
}

#define REPEAT10(M) M(0) M(1) M(2) M(3) M(4) M(5) M(6) M(7) M(8) M(9)

// ============ single-pass fused SE kernel (cooperative co-residency) ============
__global__ __launch_bounds__(NTHR, 2)
void se_fused(
    const float* __restrict__ in, const float* __restrict__ w1,
    const float* __restrict__ b1, const float* __restrict__ gamma,
    const float* __restrict__ beta, const float* __restrict__ w2,
    const float* __restrict__ b2, float* __restrict__ out,
    float* __restrict__ s, float* __restrict__ hn, unsigned* __restrict__ bar)
{
    __shared__ unsigned short ldat[LDSROWS * HW];   // 57344 B retained bf16
    __shared__ float redbuf[ROWS_PB][4];
    __shared__ float hrow[BB];
    __shared__ float grow[ROWS_PB];

    const int t   = threadIdx.x;
    const int blk = blockIdx.x;
    const int R0  = blk * ROWS_PB;
    const int wv  = t >> 6, ln = t & 63;

    // 40 named u16x4 = 80 VGPRs of retained data; fits the observed 128 budget.
#define DECLR(i) u16x4 r##i##_0, r##i##_1, r##i##_2, r##i##_3;
    REPEAT10(DECLR)
#undef DECLR

    // ---------------- phase 1: pure read stream; pool + retain ----------------
    // order: reg rows (0-9), LDS rows (10-16), reload rows (17-31) LAST so the
    // chip-wide read tail (~120MB) is L3-resident when phase 2 re-reads it first.
#define P1REG(i) { \
    const f32x4* rp = (const f32x4*)(in + (size_t)(R0 + (i)) * HW); \
    f32x4 v0 = rp[t], v1 = rp[t + 256], v2 = rp[t + 512], v3 = rp[t + 768]; \
    float part = (v0.x + v0.y + v0.z + v0.w) + (v1.x + v1.y + v1.z + v1.w) \
               + (v2.x + v2.y + v2.z + v2.w) + (v3.x + v3.y + v3.z + v3.w); \
    r##i##_0 = cvt4(v0); r##i##_1 = cvt4(v1); \
    r##i##_2 = cvt4(v2); r##i##_3 = cvt4(v3); \
    _Pragma("unroll") \
    for (int off = 32; off >= 1; off >>= 1) part += __shfl_xor(part, off, 64); \
    if (ln == 0) redbuf[(i)][wv] = part; \
}
    REPEAT10(P1REG)
#undef P1REG

    for (int lr = 0; lr < LDSROWS; ++lr) {
        const int row = NREGR + lr;
        const f32x4* rp = (const f32x4*)(in + (size_t)(R0 + row) * HW);
        float part = 0.f;
#pragma unroll
        for (int j = 0; j < 4; ++j) {
            f32x4 v = rp[t + j * NTHR];
            part += v.x + v.y + v.z + v.w;
            *(u16x4*)&ldat[lr * HW + (t + j * NTHR) * 4] = cvt4(v);
        }
#pragma unroll
        for (int off = 32; off >= 1; off >>= 1)
            part += __shfl_xor(part, off, 64);
        if (ln == 0) redbuf[row][wv] = part;
    }

    for (int lr = 0; lr < NRELOAD; ++lr) {       // tail rows: sum only
        const int row = NREGR + LDSROWS + lr;
        const f32x4* rp = (const f32x4*)(in + (size_t)(R0 + row) * HW);
        float part = 0.f;
#pragma unroll
        for (int j = 0; j < 4; ++j) {
            f32x4 v = rp[t + j * NTHR];
            part += v.x + v.y + v.z + v.w;
        }
#pragma unroll
        for (int off = 32; off >= 1; off >>= 1)
            part += __shfl_xor(part, off, 64);
        if (ln == 0) redbuf[row][wv] = part;
    }

    __syncthreads();
    if (t < ROWS_PB) {
        float sum = redbuf[t][0] + redbuf[t][1] + redbuf[t][2] + redbuf[t][3];
        s[R0 + t] = sum * (1.0f / HW);
    }
    grid_barrier(bar, 1);

    // ---------------- middle A: blocks 0..127 compute h[:,k] + BN -> hn ----------------
    if (blk < CB) {
        const int k = blk;
        const int b = t >> 3, p = t & 7;
        const f32x4* sr = (const f32x4*)(s  + b * CC + p * 64);
        const f32x4* wr = (const f32x4*)(w1 + k * CC + p * 64);
        float acc = 0.f;
#pragma unroll
        for (int j = 0; j < 16; ++j) {
            f32x4 a = sr[j], w = wr[j];
            acc += a.x * w.x + a.y * w.y + a.z * w.z + a.w * w.w;
        }
        acc += __shfl_xor(acc, 1, 64);
        acc += __shfl_xor(acc, 2, 64);
        acc += __shfl_xor(acc, 4, 64);
        if (p == 0) {
            float v = acc + b1[k];
            hrow[b] = v > 0.f ? v : 0.f;
        }
        __syncthreads();
        if (t == 0) {
            float su = 0.f, sq = 0.f;
            for (int bb = 0; bb < BB; ++bb) { float v = hrow[bb]; su += v; sq += v * v; }
            float mu  = su * (1.0f / BB);
            float var = sq * (1.0f / BB) - mu * mu;
            redbuf[0][0] = mu;
            redbuf[0][1] = gamma[k] * rsqrtf(var + 1e-5f);
        }
        __syncthreads();
        if (t < BB) {
            float mu = redbuf[0][0], sc = redbuf[0][1];
            hn[t * CB + k] = (hrow[t] - mu) * sc + beta[k];
        }
    }
    grid_barrier(bar, 2);

    // ---------------- middle B: per-block gates for its own 32 rows ----------------
    {
        const int r = t >> 3, p = t & 7;
        const int R = R0 + r;
        const int bb = R >> 9, cc = R & 511;
        const f32x4* hr = (const f32x4*)(hn + bb * CB + p * 16);
        const f32x4* wr = (const f32x4*)(w2 + cc * CB + p * 16);
        float acc = 0.f;
#pragma unroll
        for (int j = 0; j < 4; ++j) {
            f32x4 a = hr[j], w = wr[j];
            acc += a.x * w.x + a.y * w.y + a.z * w.z + a.w * w.w;
        }
        acc += __shfl_xor(acc, 1, 64);
        acc += __shfl_xor(acc, 2, 64);
        acc += __shfl_xor(acc, 4, 64);
        if (p == 0) grow[r] = 1.0f / (1.0f + expf(-(acc + b2[cc])));
    }
    __syncthreads();

    // ---------------- phase 2: reload rows FIRST (L3-hot), then LDS, then regs ----------------
    for (int lr = 0; lr < NRELOAD; ++lr) {
        const int row = NREGR + LDSROWS + lr;
        float g = grow[row];
        const f32x4* rp = (const f32x4*)(in + (size_t)(R0 + row) * HW);
        f32x4* op = (f32x4*)(out + (size_t)(R0 + row) * HW);
#pragma unroll
        for (int j = 0; j < 4; ++j) {
            f32x4 v = rp[t + j * NTHR];
            v.x *= g; v.y *= g; v.z *= g; v.w *= g;
            __builtin_nontemporal_store(v, &op[t + j * NTHR]);
        }
    }

    for (int lr = 0; lr < LDSROWS; ++lr) {
        const int row = NREGR + lr;
        float g = grow[row];
        f32x4* op = (f32x4*)(out + (size_t)(R0 + row) * HW);
#pragma unroll
        for (int j = 0; j < 4; ++j) {
            u16x4 cv = *(const u16x4*)&ldat[lr * HW + (t + j * NTHR) * 4];
            __builtin_nontemporal_store(scl4(cv, g), &op[t + j * NTHR]);
        }
    }

#define P2REG(i) { \
    float g = grow[(i)]; \
    f32x4* op = (f32x4*)(out + (size_t)(R0 + (i)) * HW); \
    __builtin_nontemporal_store(scl4(r##i##_0, g), &op[t]); \
    __builtin_nontemporal_store(scl4(r##i##_1, g), &op[t + 256]); \
    __builtin_nontemporal_store(scl4(r##i##_2, g), &op[t + 512]); \
    __builtin_nontemporal_store(scl4(r##i##_3, g), &op[t + 768]); \
}
    REPEAT10(P2REG)
#undef P2REG
}

// ============ fallback path (R3 structure, ~128 us) ============
__global__ __launch_bounds__(256) void se_pool(const float* __restrict__ in,
                                               float* __restrict__ s) {
    int bc = blockIdx.x;
    const f32x4* row = (const f32x4*)(in + (size_t)bc * HW);
    int t = threadIdx.x;
    float acc = 0.f;
#pragma unroll
    for (int i = 0; i < 4; ++i) {
        f32x4 v = row[t + i * 256];
        acc += v.x + v.y + v.z + v.w;
    }
#pragma unroll
    for (int off = 32; off >= 1; off >>= 1)
        acc += __shfl_xor(acc, off, 64);
    __shared__ float red[4];
    if ((t & 63) == 0) red[t >> 6] = acc;
    __syncthreads();
    if (t == 0) s[bc] = (red[0] + red[1] + red[2] + red[3]) * (1.0f / HW);
}

__global__ __launch_bounds__(256) void se_h(const float* __restrict__ s,
                                            const float* __restrict__ w1,
                                            const float* __restrict__ b1,
                                            float* __restrict__ h) {
    int k = blockIdx.x;
    __shared__ float wrow[CC];
    int t = threadIdx.x;
    wrow[t]       = w1[k * CC + t];
    wrow[t + 256] = w1[k * CC + t + 256];
    __syncthreads();
    int b = t >> 3, p = t & 7;
    const float* srow = s + b * CC + p * 64;
    const float* wp   = wrow + p * 64;
    float acc = 0.f;
#pragma unroll
    for (int j = 0; j < 64; ++j) acc += srow[j] * wp[j];
    acc += __shfl_xor(acc, 1, 64);
    acc += __shfl_xor(acc, 2, 64);
    acc += __shfl_xor(acc, 4, 64);
    if (p == 0) {
        float v = acc + b1[k];
        h[b * CB + k] = v > 0.f ? v : 0.f;
    }
}

__global__ __launch_bounds__(128) void se_bn(float* __restrict__ h,
                                             const float* __restrict__ gamma,
                                             const float* __restrict__ beta) {
    int k = threadIdx.x;
    float sum = 0.f, sumsq = 0.f;
#pragma unroll
    for (int b = 0; b < BB; ++b) {
        float v = h[b * CB + k];
        sum += v; sumsq += v * v;
    }
    float mu  = sum * (1.0f / BB);
    float var = sumsq * (1.0f / BB) - mu * mu;
    float sc  = gamma[k] * rsqrtf(var + 1e-5f);
    float sh  = beta[k] - mu * sc;
#pragma unroll
    for (int b = 0; b < BB; ++b)
        h[b * CB + k] = h[b * CB + k] * sc + sh;
}

__global__ __launch_bounds__(256) void se_mul(const float* __restrict__ in,
                                              const float* __restrict__ hn,
                                              const float* __restrict__ w2,
                                              const float* __restrict__ b2,
                                              float* __restrict__ out) {
    int bc = (NROW - 1) - blockIdx.x;
    int b = bc >> 9, c = bc & 511;
    const f32x4* hv = (const f32x4*)(hn + b * CB);
    const f32x4* wv = (const f32x4*)(w2 + c * CB);
    float acc = 0.f;
#pragma unroll
    for (int i = 0; i < 32; ++i) {
        f32x4 a = hv[i], w = wv[i];
        acc += a.x * w.x + a.y * w.y + a.z * w.z + a.w * w.w;
    }
    float g = 1.0f / (1.0f + expf(-(acc + b2[c])));
    const f32x4* iv = (const f32x4*)(in + (size_t)bc * HW);
    f32x4* ov       = (f32x4*)(out + (size_t)bc * HW);
    int t = threadIdx.x;
#pragma unroll
    for (int i = 0; i < 4; ++i) {
        f32x4 v = iv[t + i * 256];
        v.x *= g; v.y *= g; v.z *= g; v.w *= g;
        __builtin_nontemporal_store(v, &ov[t + i * 256]);
    }
}

extern "C" void kernel_launch(void* const* d_in, const int* in_sizes, int n_in,
                              void* d_out, int out_size, void* d_ws, size_t ws_size,
                              hipStream_t stream) {
    const float* in    = (const float*)d_in[0];
    const float* w1    = (const float*)d_in[1];
    const float* b1    = (const float*)d_in[2];
    const float* gamma = (const float*)d_in[3];
    const float* beta  = (const float*)d_in[4];
    const float* w2    = (const float*)d_in[5];
    const float* b2    = (const float*)d_in[6];
    float* out = (float*)d_out;

    unsigned* bar = (unsigned*)d_ws;                       // 4 KB barrier counters
    float* s  = (float*)((char*)d_ws + 4096);              // 16384 floats
    float* hn = s + NROW;                                  // 4096 floats

    hipMemsetAsync(bar, 0, 4096, stream);                  // graph-legal, per-call

    void* args[] = { (void*)&in, (void*)&w1, (void*)&b1, (void*)&gamma,
                     (void*)&beta, (void*)&w2, (void*)&b2, (void*)&out,
                     (void*)&s, (void*)&hn, (void*)&bar };
    hipError_t e = hipLaunchCooperativeKernel((const void*)se_fused,
                                              dim3(NBLK), dim3(NTHR),
                                              args, 0, stream);
    if (e != hipSuccess) {
        se_pool<<<NROW, 256, 0, stream>>>(in, s);
        se_h<<<CB, 256, 0, stream>>>(s, w1, b1, hn);
        se_bn<<<1, CB, 0, stream>>>(hn, gamma, beta);
        se_mul<<<NROW, 256, 0, stream>>>(in, hn, w2, b2, out);
    }
}